// Round 6
// baseline (1078.517 us; speedup 1.0000x reference)
//
#include <hip/hip_runtime.h>
#include <math.h>

// ---- composite-sort geometry ----
#define TPB 512                 // hist/scan/bin block
#define TPB_R 1024              // reduce/combine block
#define WIN_SHIFT 14
#define WIN_SIZE 16384          // nodes per dst-window AND per src-window
#define WIN_MASK (WIN_SIZE - 1)
#define MAXW 64                 // max windows per axis (N <= 2^20)
#define MAXK 4096               // max composite buckets (MAXW*MAXW)
#define TILE 32768              // edges per tile (hist/bin grid dim)
#define SUB 16384               // edges per bin sub-chunk
#define SPLITR 4                // reduce blocks per dst-window

typedef int          int4n   __attribute__((ext_vector_type(4)));
typedef unsigned int uint4n  __attribute__((ext_vector_type(4)));
typedef float        float4n __attribute__((ext_vector_type(4)));

// ---------- scan helpers ----------

__device__ inline unsigned wave_scan_incl(unsigned v) {
#pragma unroll
    for (int d = 1; d < 64; d <<= 1) {
        unsigned n = __shfl_up(v, d, 64);
        if ((int)(threadIdx.x & 63) >= d) v += n;
    }
    return v;
}

// Exclusive scan over 4096 values, 8 per thread (TPB=512). wtot: 8-entry LDS.
__device__ inline void block_excl_scan_4096(const unsigned a[8], unsigned* wtot,
                                            unsigned e[8]) {
    unsigned s = 0;
#pragma unroll
    for (int i = 0; i < 8; ++i) s += a[i];
    unsigned incl = wave_scan_incl(s);
    int lane = threadIdx.x & 63, wid = threadIdx.x >> 6;
    if (lane == 63) wtot[wid] = incl;
    __syncthreads();
    if (threadIdx.x == 0) {
        unsigned c = 0;
#pragma unroll
        for (int i = 0; i < 8; ++i) { unsigned tv = wtot[i]; wtot[i] = c; c += tv; }
    }
    __syncthreads();
    unsigned base = wtot[wid] + incl - s;
#pragma unroll
    for (int i = 0; i < 8; ++i) { e[i] = base; base += a[i]; }
}

// Exclusive scan over 1024 values, 2 per thread (TPB=512).
__device__ inline void block_excl_scan_1024(unsigned a0, unsigned a1,
                                            unsigned* wtot,
                                            unsigned& e0, unsigned& e1) {
    unsigned s = a0 + a1;
    unsigned incl = wave_scan_incl(s);
    int lane = threadIdx.x & 63, wid = threadIdx.x >> 6;
    if (lane == 63) wtot[wid] = incl;
    __syncthreads();
    if (threadIdx.x == 0) {
        unsigned c = 0;
#pragma unroll
        for (int i = 0; i < 8; ++i) { unsigned tv = wtot[i]; wtot[i] = c; c += tv; }
    }
    __syncthreads();
    unsigned base = wtot[wid] + incl - s;
    e0 = base;
    e1 = base + a0;
}

// ---------- K1: per-tile composite-bucket histogram (2-way privatized) ----------

__global__ __launch_bounds__(TPB)
void hist_kernel(const int* __restrict__ src, const int* __restrict__ dst,
                 unsigned* __restrict__ counts,
                 long long E, int NK, int NSW, int G) {
    __shared__ unsigned hist[2 * MAXK];   // 32 KB, one copy per half-block
    int g = blockIdx.x, t = threadIdx.x;
    for (int i = t; i < 2 * MAXK; i += TPB) hist[i] = 0;
    __syncthreads();
    unsigned* h = hist + ((t >> 8) << 12);   // threads 0-255 / 256-511
    long long start = (long long)g * TILE;
    long long end = start + TILE; if (end > E) end = E;
    long long nfull4 = (end - start) >> 2;
    const int4n* s4 = (const int4n*)(src + start);
    const int4n* d4 = (const int4n*)(dst + start);
    for (long long v = t; v < nfull4; v += TPB) {
        int4n sv = __builtin_nontemporal_load(s4 + v);
        int4n dv = __builtin_nontemporal_load(d4 + v);
        atomicAdd(&h[(((unsigned)dv.x) >> WIN_SHIFT) * NSW + (((unsigned)sv.x) >> WIN_SHIFT)], 1u);
        atomicAdd(&h[(((unsigned)dv.y) >> WIN_SHIFT) * NSW + (((unsigned)sv.y) >> WIN_SHIFT)], 1u);
        atomicAdd(&h[(((unsigned)dv.z) >> WIN_SHIFT) * NSW + (((unsigned)sv.z) >> WIN_SHIFT)], 1u);
        atomicAdd(&h[(((unsigned)dv.w) >> WIN_SHIFT) * NSW + (((unsigned)sv.w) >> WIN_SHIFT)], 1u);
    }
    for (long long e = start + nfull4 * 4 + t; e < end; e += TPB)
        atomicAdd(&h[(((unsigned)dst[e]) >> WIN_SHIFT) * NSW + (((unsigned)src[e]) >> WIN_SHIFT)], 1u);
    __syncthreads();
    for (int b = t; b < NK; b += TPB)
        counts[(size_t)b * G + g] = hist[b] + hist[MAXK + b];
}

// ---------- K2a: exclusive scan of each bucket row (over tiles) ----------

__global__ __launch_bounds__(TPB)
void scan_rows(unsigned* __restrict__ counts, unsigned* __restrict__ rowTotal,
               int G) {
    __shared__ unsigned wtot[8];
    int b = blockIdx.x, t = threadIdx.x;
    int g0 = 2 * t, g1 = 2 * t + 1;
    unsigned a0 = (g0 < G) ? counts[(size_t)b * G + g0] : 0u;
    unsigned a1 = (g1 < G) ? counts[(size_t)b * G + g1] : 0u;
    unsigned e0, e1;
    block_excl_scan_1024(a0, a1, wtot, e0, e1);
    if (g0 < G) counts[(size_t)b * G + g0] = e0;
    if (g1 < G) counts[(size_t)b * G + g1] = e1;
    if (t == TPB - 1) rowTotal[b] = e1 + a1;
}

// ---------- K2b: exclusive scan of bucket totals (4096-wide) ----------

__global__ __launch_bounds__(TPB)
void scan_buckets(const unsigned* __restrict__ rowTotal,
                  unsigned* __restrict__ bucketStart, int NK) {
    __shared__ unsigned wtot[8];
    int t = threadIdx.x;
    unsigned a[8], e[8];
#pragma unroll
    for (int i = 0; i < 8; ++i) {
        int idx = 8 * t + i;
        a[i] = (idx < NK) ? rowTotal[idx] : 0u;
    }
    block_excl_scan_4096(a, wtot, e);
#pragma unroll
    for (int i = 0; i < 8; ++i) {
        int idx = 8 * t + i;
        if (idx <= NK) bucketStart[idx] = e[i];
    }
}

// ---------- K3: tile-local counting sort by composite key ----------
// Two passes over each sub-chunk (recompute keys) to keep VGPRs low.

__global__ __launch_bounds__(TPB)
void bin_kernel(const int* __restrict__ src, const int* __restrict__ dst,
                const unsigned* __restrict__ counts,
                const unsigned* __restrict__ bucketStart,
                unsigned* __restrict__ packed,
                long long E, int NK, int NSW, int G) {
    __shared__ unsigned cursor[MAXK];        // 16 KB
    __shared__ unsigned A[MAXK];             // 16 KB  (excl starts)
    __shared__ unsigned B[MAXK];             // 16 KB  (rank cursors)
    __shared__ unsigned wtot[8];
    __shared__ unsigned short sKey[SUB];     // 32 KB
    __shared__ unsigned sPack[SUB];          // 64 KB   -> ~144 KB total
    int g = blockIdx.x, t = threadIdx.x;

    for (int b = t; b < NK; b += TPB)
        cursor[b] = bucketStart[b] + counts[(size_t)b * G + g];

    long long tileStart = (long long)g * TILE;
    long long tileEnd = tileStart + TILE; if (tileEnd > E) tileEnd = E;

    for (long long subBase = tileStart; subBase < tileEnd; subBase += SUB) {
        long long rem = tileEnd - subBase;
        int subCount = (rem < (long long)SUB) ? (int)rem : SUB;

        for (int b = t; b < MAXK; b += TPB) A[b] = 0u;
        __syncthreads();

        // pass 1: histogram keys (SUB/4/TPB = 8 vector iters)
#pragma unroll
        for (int r = 0; r < SUB / 4 / TPB; ++r) {
            long long ebase = subBase + ((long long)(r * TPB + t)) * 4;
            if (ebase + 4 <= tileEnd) {
                int4n sv = __builtin_nontemporal_load((const int4n*)(src + ebase));
                int4n dv = __builtin_nontemporal_load((const int4n*)(dst + ebase));
                atomicAdd(&A[(((unsigned)dv.x) >> WIN_SHIFT) * NSW + (((unsigned)sv.x) >> WIN_SHIFT)], 1u);
                atomicAdd(&A[(((unsigned)dv.y) >> WIN_SHIFT) * NSW + (((unsigned)sv.y) >> WIN_SHIFT)], 1u);
                atomicAdd(&A[(((unsigned)dv.z) >> WIN_SHIFT) * NSW + (((unsigned)sv.z) >> WIN_SHIFT)], 1u);
                atomicAdd(&A[(((unsigned)dv.w) >> WIN_SHIFT) * NSW + (((unsigned)sv.w) >> WIN_SHIFT)], 1u);
            } else {
                for (long long e = ebase; e < tileEnd; ++e)
                    atomicAdd(&A[(((unsigned)dst[e]) >> WIN_SHIFT) * NSW + (((unsigned)src[e]) >> WIN_SHIFT)], 1u);
            }
        }
        __syncthreads();

        // scan A -> exclusive starts; copy to B as running rank cursors
        {
            unsigned a[8], e[8];
#pragma unroll
            for (int i = 0; i < 8; ++i) a[i] = A[8 * t + i];
            block_excl_scan_4096(a, wtot, e);
#pragma unroll
            for (int i = 0; i < 8; ++i) { A[8 * t + i] = e[i]; B[8 * t + i] = e[i]; }
        }
        __syncthreads();

        // pass 2: recompute keys, rank, scatter into sorted LDS staging
#pragma unroll
        for (int r = 0; r < SUB / 4 / TPB; ++r) {
            long long ebase = subBase + ((long long)(r * TPB + t)) * 4;
            if (ebase + 4 <= tileEnd) {
                int4n sv = __builtin_nontemporal_load((const int4n*)(src + ebase));
                int4n dv = __builtin_nontemporal_load((const int4n*)(dst + ebase));
                unsigned dd[4] = {(unsigned)dv.x, (unsigned)dv.y, (unsigned)dv.z, (unsigned)dv.w};
                unsigned ss[4] = {(unsigned)sv.x, (unsigned)sv.y, (unsigned)sv.z, (unsigned)sv.w};
#pragma unroll
                for (int c = 0; c < 4; ++c) {
                    unsigned k = (dd[c] >> WIN_SHIFT) * NSW + (ss[c] >> WIN_SHIFT);
                    unsigned rk = atomicAdd(&B[k], 1u);
                    sKey[rk] = (unsigned short)k;
                    sPack[rk] = ((dd[c] & WIN_MASK) << WIN_SHIFT) | (ss[c] & WIN_MASK);
                }
            } else {
                for (long long e = ebase; e < tileEnd; ++e) {
                    unsigned d = (unsigned)dst[e], s = (unsigned)src[e];
                    unsigned k = (d >> WIN_SHIFT) * NSW + (s >> WIN_SHIFT);
                    unsigned rk = atomicAdd(&B[k], 1u);
                    sKey[rk] = (unsigned short)k;
                    sPack[rk] = ((d & WIN_MASK) << WIN_SHIFT) | (s & WIN_MASK);
                }
            }
        }
        __syncthreads();

        // flush sorted staging: consecutive jj within a bucket run ->
        // consecutive global slots (runs merge across sub-chunks in L2)
        for (int jj = t; jj < subCount; jj += TPB) {
            unsigned b = sKey[jj];
            unsigned gpos = cursor[b] + (unsigned)jj - A[b];
            packed[gpos] = sPack[jj];
        }
        __syncthreads();

        // advance cursors
        for (int b = t; b < NK; b += TPB) {
            unsigned nextA = (b + 1 < MAXK) ? A[b + 1] : (unsigned)subCount;
            cursor[b] += nextA - A[b];
        }
        __syncthreads();
    }
}

// ---------- K4: LDS-staged reduce ----------
// Block (dw, s): accumulates dst-window dw over src-windows [s*CH, s*CH+CH).
// All value gathers hit LDS; the only global reads are coalesced.

__global__ __launch_bounds__(TPB_R)
void reduce_staged(const unsigned* __restrict__ packed,
                   const unsigned* __restrict__ bucketStart,
                   const float* __restrict__ in,
                   float* __restrict__ part,
                   int N, int NSW, int CH) {
    __shared__ float acc[WIN_SIZE];   // 64 KB dst-window accumulator
    __shared__ float xs[WIN_SIZE];    // 64 KB staged src-window
    int blk = blockIdx.x, t = threadIdx.x;
    int dw = blk / SPLITR, s = blk % SPLITR;
    for (int k = t; k < WIN_SIZE; k += TPB_R) acc[k] = 0.f;

    int w0 = s * CH, w1 = w0 + CH; if (w1 > NSW) w1 = NSW;
    for (int w = w0; w < w1; ++w) {
        __syncthreads();   // previous window's readers done before restage
        // stage src-window w (coalesced; re-reads served by L2 — in[] is 4 MB)
        int nodeBase = w << WIN_SHIFT;
        if (nodeBase + WIN_SIZE <= N) {
            const float4n* f4 = (const float4n*)(in + nodeBase);
#pragma unroll
            for (int r = 0; r < WIN_SIZE / 4 / TPB_R; ++r) {
                int i = r * TPB_R + t;
                float4n f = f4[i];
                *(float4n*)(xs + 4 * i) = f;
            }
        } else {
            for (int i = t; i < WIN_SIZE; i += TPB_R) {
                int idx = nodeBase + i;
                xs[i] = (idx < N) ? in[idx] : 0.f;
            }
        }
        __syncthreads();

        int k = dw * NSW + w;
        unsigned segS = bucketStart[k], segE = bucketStart[k + 1];
        unsigned j = segS + (unsigned)t;
        for (; j + 3u * TPB_R < segE; j += 4u * TPB_R) {
            unsigned p0 = __builtin_nontemporal_load(packed + j);
            unsigned p1 = __builtin_nontemporal_load(packed + j + TPB_R);
            unsigned p2 = __builtin_nontemporal_load(packed + j + 2u * TPB_R);
            unsigned p3 = __builtin_nontemporal_load(packed + j + 3u * TPB_R);
            float v0 = fmaxf(xs[p0 & WIN_MASK], 0.f);
            float v1 = fmaxf(xs[p1 & WIN_MASK], 0.f);
            float v2 = fmaxf(xs[p2 & WIN_MASK], 0.f);
            float v3 = fmaxf(xs[p3 & WIN_MASK], 0.f);
            atomicAdd(&acc[p0 >> WIN_SHIFT], v0);
            atomicAdd(&acc[p1 >> WIN_SHIFT], v1);
            atomicAdd(&acc[p2 >> WIN_SHIFT], v2);
            atomicAdd(&acc[p3 >> WIN_SHIFT], v3);
        }
        for (; j < segE; j += TPB_R) {
            unsigned p = __builtin_nontemporal_load(packed + j);
            atomicAdd(&acc[p >> WIN_SHIFT], fmaxf(xs[p & WIN_MASK], 0.f));
        }
    }
    __syncthreads();
    float* dstp = part + (size_t)blk * WIN_SIZE;
    for (int k = t; k < WIN_SIZE; k += TPB_R) dstp[k] = acc[k];
}

// ---------- K5: combine SPLITR partials per dst-window, optional sigmoid ----------

__global__ __launch_bounds__(TPB_R)
void combine_kernel(const float* __restrict__ part, float* __restrict__ out,
                    int N, int act) {
    int dw = blockIdx.x, t = threadIdx.x;
    for (int k = t; k < WIN_SIZE; k += TPB_R) {
        int node = (dw << WIN_SHIFT) + k;
        if (node < N) {
            float v = 0.f;
#pragma unroll
            for (int s = 0; s < SPLITR; ++s)
                v += part[(size_t)(dw * SPLITR + s) * WIN_SIZE + k];
            out[node] = act ? 1.f / (1.f + expf(-v)) : v;
        }
    }
}

// ---------- fallback (round-1 atomic path) ----------

__global__ void scatter_add_relu(const int* __restrict__ src,
                                 const int* __restrict__ dst,
                                 const float* __restrict__ in,
                                 float* __restrict__ out,
                                 long long E, long long E4) {
    long long i = (long long)blockIdx.x * blockDim.x + threadIdx.x;
    long long stride = (long long)gridDim.x * blockDim.x;
    const int4* src4 = (const int4*)src;
    const int4* dst4 = (const int4*)dst;
    for (long long v = i; v < E4; v += stride) {
        int4 s = src4[v];
        int4 d = dst4[v];
        atomicAdd(&out[d.x], fmaxf(in[s.x], 0.0f));
        atomicAdd(&out[d.y], fmaxf(in[s.y], 0.0f));
        atomicAdd(&out[d.z], fmaxf(in[s.z], 0.0f));
        atomicAdd(&out[d.w], fmaxf(in[s.w], 0.0f));
    }
    for (long long e = E4 * 4 + i; e < E; e += stride)
        atomicAdd(&out[dst[e]], fmaxf(in[src[e]], 0.0f));
}

__global__ void sigmoid_inplace(float* __restrict__ out, int n) {
    int i = blockIdx.x * blockDim.x + threadIdx.x;
    if (i < n) {
        float v = out[i];
        out[i] = 1.0f / (1.0f + expf(-v));
    }
}

// ---------- launch ----------

extern "C" void kernel_launch(void* const* d_in, const int* in_sizes, int n_in,
                              void* d_out, int out_size, void* d_ws, size_t ws_size,
                              hipStream_t stream) {
    const float* x = (const float*)d_in[0];
    const int* ei = (const int*)d_in[1];
    const int N = in_sizes[0];
    const long long E = (long long)in_sizes[1] / 2;
    const int* src = ei;
    const int* dst = ei + E;
    float* out = (float*)d_out;

    const int NDW = (N + WIN_SIZE - 1) / WIN_SIZE;   // dst windows
    const int NSW = NDW;                             // src windows (same size)
    const int NK = NDW * NSW;                        // composite buckets
    const int G = (int)((E + TILE - 1) / TILE);
    const int CH = (NSW + SPLITR - 1) / SPLITR;

    size_t off = 0;
    auto alloc = [&](size_t bytes) {
        size_t o = off;
        off = (off + bytes + 255) & ~(size_t)255;
        return o;
    };
    char* ws = (char*)d_ws;
    size_t countsOff = alloc((size_t)NK * (size_t)G * 4);
    size_t rowTotOff = alloc((size_t)NK * 4);
    size_t bsOff     = alloc((size_t)(NK + 1) * 4);
    size_t h1Off     = alloc((size_t)N * 4);
    size_t packedOff = alloc((size_t)E * 4);
    size_t partOff   = alloc((size_t)NDW * SPLITR * WIN_SIZE * 4);
    size_t needed    = off;

    const bool fast = (NDW <= MAXW) && (NK <= MAXK) && (G <= 2 * TPB) &&
                      (needed <= ws_size);

    if (fast) {
        unsigned* counts = (unsigned*)(ws + countsOff);
        unsigned* rowTot = (unsigned*)(ws + rowTotOff);
        unsigned* bstart = (unsigned*)(ws + bsOff);
        float*    h1     = (float*)(ws + h1Off);
        unsigned* packed = (unsigned*)(ws + packedOff);
        float*    part   = (float*)(ws + partOff);

        hist_kernel<<<G, TPB, 0, stream>>>(src, dst, counts, E, NK, NSW, G);
        scan_rows<<<NK, TPB, 0, stream>>>(counts, rowTot, G);
        scan_buckets<<<1, TPB, 0, stream>>>(rowTot, bstart, NK);
        bin_kernel<<<G, TPB, 0, stream>>>(src, dst, counts, bstart, packed,
                                          E, NK, NSW, G);
        // layer 1: h1 = scatter_add(x[src])      (relu no-op, applied at read)
        reduce_staged<<<NDW * SPLITR, TPB_R, 0, stream>>>(packed, bstart, x,
                                                          part, N, NSW, CH);
        combine_kernel<<<NDW, TPB_R, 0, stream>>>(part, h1, N, 0);
        // layer 2: out = sigmoid(scatter_add(relu(h1[src])))
        reduce_staged<<<NDW * SPLITR, TPB_R, 0, stream>>>(packed, bstart, h1,
                                                          part, N, NSW, CH);
        combine_kernel<<<NDW, TPB_R, 0, stream>>>(part, out, N, 1);
    } else {
        float* h1 = (float*)ws;
        (void)hipMemsetAsync(h1, 0, (size_t)N * sizeof(float), stream);
        (void)hipMemsetAsync(out, 0, (size_t)N * sizeof(float), stream);
        const long long E4 = ((E & 3) == 0) ? (E >> 2) : 0;
        const long long work = (E4 > 0) ? E4 : E;
        long long blocks_ll = (work + 255) / 256;
        if (blocks_ll > 131072) blocks_ll = 131072;
        const int blocks = (int)blocks_ll;
        scatter_add_relu<<<blocks, 256, 0, stream>>>(src, dst, x, h1, E, E4);
        scatter_add_relu<<<blocks, 256, 0, stream>>>(src, dst, h1, out, E, E4);
        sigmoid_inplace<<<(N + 255) / 256, 256, 0, stream>>>(out, N);
    }
}